// Round 1
// baseline (917.418 us; speedup 1.0000x reference)
//
#include <hip/hip_runtime.h>
#include <math.h>

// ---------------------------------------------------------------------------
// GraphSAGE (2x SAGEConv mean + FC + sigmoid) on MI355X.
// Pipeline:
//   1) degree histogram (int atomics)
//   2) exclusive scan -> CSR offsets (3-kernel hierarchical scan)
//   3) scatter-fill CSR (src lists grouped by dst)
//   4) agg128: mean-aggregate x over neighbors -> M [N,128]
//   5) gemm<1>: H1 = relu(M@W1l + x@W1r + b1)          [N,128]
//   6) gemm<2>: P  = H1 @ [W2l | W2r]                  [N,128]  (cols 0-63 = h1@W2l, 64-127 = h1@W2r)
//   7) final: per node, mean-aggregate P[:,0:64] over neighbors, add P[n,64:]+b2,
//             relu, dot with Wfc, sigmoid -> out[n]
// Uses mean(h1)@W2l == mean(h1@W2l) to halve layer-2 gather bytes.
// ---------------------------------------------------------------------------

__global__ __launch_bounds__(256) void k_count(const int* __restrict__ dst,
                                               int* __restrict__ cnt, int E) {
  int stride = gridDim.x * blockDim.x;
  for (int e = blockIdx.x * blockDim.x + threadIdx.x; e < E; e += stride)
    atomicAdd(&cnt[dst[e]], 1);
}

__global__ __launch_bounds__(256) void k_scan_block(const int* __restrict__ cnt,
                                                    int* __restrict__ off,
                                                    int* __restrict__ bsum, int n) {
  __shared__ int sh[256];
  int t = threadIdx.x;
  int i = blockIdx.x * 256 + t;
  int v = (i < n) ? cnt[i] : 0;
  sh[t] = v;
  __syncthreads();
  int x = v;
  for (int d = 1; d < 256; d <<= 1) {
    int y = (t >= d) ? sh[t - d] : 0;
    __syncthreads();
    x += y;
    sh[t] = x;
    __syncthreads();
  }
  if (i < n) off[i] = x - v;          // exclusive within block
  if (t == 255) bsum[blockIdx.x] = x; // block total
}

__global__ void k_scan_partials(int* bsum, int nb) {
  // nb must be <= 512 (N=100000 -> nb=391)
  __shared__ int sh[512];
  int t = threadIdx.x;
  int v = (t < nb) ? bsum[t] : 0;
  sh[t] = v;
  __syncthreads();
  int x = v;
  for (int d = 1; d < 512; d <<= 1) {
    int y = (t >= d) ? sh[t - d] : 0;
    __syncthreads();
    x += y;
    sh[t] = x;
    __syncthreads();
  }
  if (t < nb) bsum[t] = x - v; // exclusive block base
}

__global__ __launch_bounds__(256) void k_scan_add(int* __restrict__ off,
                                                  const int* __restrict__ bsum,
                                                  int n, int total) {
  int i = blockIdx.x * 256 + threadIdx.x;
  if (i < n) off[i] += bsum[blockIdx.x];
  if (i == 0) off[n] = total;
}

__global__ __launch_bounds__(256) void k_fill(const int* __restrict__ src,
                                              const int* __restrict__ dst,
                                              int* __restrict__ cur,
                                              int* __restrict__ csr, int E) {
  int stride = gridDim.x * blockDim.x;
  for (int e = blockIdx.x * blockDim.x + threadIdx.x; e < E; e += stride) {
    int d = dst[e];
    int p = atomicAdd(&cur[d], 1);
    csr[p] = src[e];
  }
}

// wave-per-node mean aggregation of 128-dim rows: M[n] = mean_{s in N(n)} x[s]
__global__ __launch_bounds__(256) void k_agg128(const float* __restrict__ x,
                                                const int* __restrict__ off,
                                                const int* __restrict__ csr,
                                                float* __restrict__ M, int n) {
  int lane = threadIdx.x & 63;
  int node = blockIdx.x * 4 + (threadIdx.x >> 6);
  if (node >= n) return;
  int s = off[node], e = off[node + 1];
  const float2* X = (const float2*)x;
  float ax0 = 0, ay0 = 0, ax1 = 0, ay1 = 0, ax2 = 0, ay2 = 0, ax3 = 0, ay3 = 0;
  int i = s;
  for (; i + 4 <= e; i += 4) {
    int s0 = csr[i], s1 = csr[i + 1], s2 = csr[i + 2], s3 = csr[i + 3];
    float2 v0 = X[(size_t)s0 * 64 + lane];
    float2 v1 = X[(size_t)s1 * 64 + lane];
    float2 v2 = X[(size_t)s2 * 64 + lane];
    float2 v3 = X[(size_t)s3 * 64 + lane];
    ax0 += v0.x; ay0 += v0.y;
    ax1 += v1.x; ay1 += v1.y;
    ax2 += v2.x; ay2 += v2.y;
    ax3 += v3.x; ay3 += v3.y;
  }
  for (; i < e; ++i) {
    int s0 = csr[i];
    float2 v0 = X[(size_t)s0 * 64 + lane];
    ax0 += v0.x; ay0 += v0.y;
  }
  int deg = e - s;
  float inv = 1.0f / (float)(deg > 0 ? deg : 1);
  float2 r;
  r.x = (ax0 + ax1 + ax2 + ax3) * inv;
  r.y = (ay0 + ay1 + ay2 + ay3) * inv;
  ((float2*)M)[(size_t)node * 64 + lane] = r;
}

// Tiled fp32 GEMM, tile 64 rows x 128 cols, K chunked by 64 in LDS.
// MODE 1: C = relu(A1@Wa + A2@Wb + bias)   (Wa,Wb: [128,128])
// MODE 2: C = A1 @ [Wa | Wb]               (Wa,Wb: [128,64]), no bias/relu
template <int MODE>
__global__ __launch_bounds__(256) void k_gemm128(const float* __restrict__ A1,
                                                 const float* __restrict__ Wa,
                                                 const float* __restrict__ A2,
                                                 const float* __restrict__ Wb,
                                                 const float* __restrict__ bias,
                                                 float* __restrict__ C, int nrows) {
  __shared__ float Al[64][68];   // stride 68 keeps float4 writes 16B-aligned; A reads 2-way alias (free)
  __shared__ float Wl[64][128];
  int t = threadIdx.x;
  int tx = t & 15, ty = t >> 4;
  int rowbase = blockIdx.x * 64;
  float acc[4][8];
#pragma unroll
  for (int i = 0; i < 4; ++i)
#pragma unroll
    for (int j = 0; j < 8; ++j) acc[i][j] = 0.f;

  const int nmat = (MODE == 1) ? 2 : 1;
  for (int m = 0; m < nmat; ++m) {
    const float* A = (m == 0) ? A1 : A2;
    const float* W = (m == 0) ? Wa : Wb;
    (void)W;
    for (int k0 = 0; k0 < 128; k0 += 64) {
      { // stage A tile [64][64]
        int tc = t & 15, tr = t >> 4;
#pragma unroll
        for (int p = 0; p < 4; ++p) {
          int row = tr + p * 16;
          int gr = rowbase + row;
          float4 v = make_float4(0.f, 0.f, 0.f, 0.f);
          if (gr < nrows) v = *(const float4*)&A[(size_t)gr * 128 + k0 + tc * 4];
          *(float4*)&Al[row][tc * 4] = v;
        }
      }
      { // stage W tile [64][128]
        int tc = t & 31, tr = t >> 5;
#pragma unroll
        for (int p = 0; p < 8; ++p) {
          int kk = tr + p * 8;
          float4 v;
          if (MODE == 1) {
            v = *(const float4*)&W[(size_t)(k0 + kk) * 128 + tc * 4];
          } else {
            int c = tc * 4;
            if (c < 64) v = *(const float4*)&Wa[(size_t)(k0 + kk) * 64 + c];
            else        v = *(const float4*)&Wb[(size_t)(k0 + kk) * 64 + (c - 64)];
          }
          *(float4*)&Wl[kk][tc * 4] = v;
        }
      }
      __syncthreads();
#pragma unroll 4
      for (int kk = 0; kk < 64; ++kk) {
        float4 w0 = *(float4*)&Wl[kk][tx * 8];
        float4 w1 = *(float4*)&Wl[kk][tx * 8 + 4];
#pragma unroll
        for (int i2 = 0; i2 < 4; ++i2) {
          float a = Al[ty * 4 + i2][kk];
          acc[i2][0] += a * w0.x; acc[i2][1] += a * w0.y;
          acc[i2][2] += a * w0.z; acc[i2][3] += a * w0.w;
          acc[i2][4] += a * w1.x; acc[i2][5] += a * w1.y;
          acc[i2][6] += a * w1.z; acc[i2][7] += a * w1.w;
        }
      }
      __syncthreads();
    }
  }
  float4 bv0 = make_float4(0.f, 0.f, 0.f, 0.f), bv1 = bv0;
  if (MODE == 1) {
    bv0 = *(const float4*)&bias[tx * 8];
    bv1 = *(const float4*)&bias[tx * 8 + 4];
  }
#pragma unroll
  for (int i2 = 0; i2 < 4; ++i2) {
    int gr = rowbase + ty * 4 + i2;
    if (gr >= nrows) continue;
    float o[8];
#pragma unroll
    for (int j = 0; j < 8; ++j) o[j] = acc[i2][j];
    if (MODE == 1) {
      o[0] += bv0.x; o[1] += bv0.y; o[2] += bv0.z; o[3] += bv0.w;
      o[4] += bv1.x; o[5] += bv1.y; o[6] += bv1.z; o[7] += bv1.w;
#pragma unroll
      for (int j = 0; j < 8; ++j) o[j] = fmaxf(o[j], 0.f);
    }
    *(float4*)&C[(size_t)gr * 128 + tx * 8]     = make_float4(o[0], o[1], o[2], o[3]);
    *(float4*)&C[(size_t)gr * 128 + tx * 8 + 4] = make_float4(o[4], o[5], o[6], o[7]);
  }
}

// wave-per-node: mean-aggregate P[:,0:64], add P[n,64:128]+b2, relu, dot Wfc, sigmoid
__global__ __launch_bounds__(256) void k_final(const float* __restrict__ P,
                                               const int* __restrict__ off,
                                               const int* __restrict__ csr,
                                               const float* __restrict__ b2,
                                               const float* __restrict__ Wfc,
                                               const float* __restrict__ bfc,
                                               float* __restrict__ out, int n) {
  int lane = threadIdx.x & 63;
  int node = blockIdx.x * 4 + (threadIdx.x >> 6);
  if (node >= n) return;
  int s = off[node], e = off[node + 1];
  float a0 = 0, a1 = 0, a2 = 0, a3 = 0;
  int i = s;
  for (; i + 4 <= e; i += 4) {
    int s0 = csr[i], s1 = csr[i + 1], s2 = csr[i + 2], s3 = csr[i + 3];
    a0 += P[(size_t)s0 * 128 + lane];
    a1 += P[(size_t)s1 * 128 + lane];
    a2 += P[(size_t)s2 * 128 + lane];
    a3 += P[(size_t)s3 * 128 + lane];
  }
  for (; i < e; ++i) a0 += P[(size_t)csr[i] * 128 + lane];
  int deg = e - s;
  float inv = 1.0f / (float)(deg > 0 ? deg : 1);
  float h = (a0 + a1 + a2 + a3) * inv + P[(size_t)node * 128 + 64 + lane] + b2[lane];
  h = fmaxf(h, 0.f);
  float v = h * Wfc[lane];
#pragma unroll
  for (int o2 = 32; o2 > 0; o2 >>= 1) v += __shfl_xor(v, o2, 64);
  if (lane == 0) out[node] = 1.0f / (1.0f + expf(-(v + bfc[0])));
}

extern "C" void kernel_launch(void* const* d_in, const int* in_sizes, int n_in,
                              void* d_out, int out_size, void* d_ws, size_t ws_size,
                              hipStream_t stream) {
  const float* x   = (const float*)d_in[0];
  const int*   ei  = (const int*)d_in[1];
  const float* W1l = (const float*)d_in[2];
  const float* b1  = (const float*)d_in[3];
  const float* W1r = (const float*)d_in[4];
  const float* W2l = (const float*)d_in[5];
  const float* b2  = (const float*)d_in[6];
  const float* W2r = (const float*)d_in[7];
  const float* Wfc = (const float*)d_in[8];
  const float* bfc = (const float*)d_in[9];
  float* out = (float*)d_out;

  const int N = in_sizes[0] / 128;
  const int E = in_sizes[1] / 2;
  const int* srcp = ei;       // edge_index[0]
  const int* dstp = ei + E;   // edge_index[1]

  // workspace layout (256B aligned regions), total ~117 MB
  char* w = (char*)d_ws;
  auto alloc = [&](size_t bytes) -> void* {
    void* p = (void*)w;
    w += (bytes + 255) & ~(size_t)255;
    return p;
  };
  int*   off  = (int*)alloc((size_t)(N + 1) * 4);
  int*   cur  = (int*)alloc((size_t)N * 4);        // degree counts, then CSR cursors
  int*   bsum = (int*)alloc(4096);
  int*   csr  = (int*)alloc((size_t)E * 4);
  float* M    = (float*)alloc((size_t)N * 128 * 4); // mean-agg, later reused as P
  float* H1   = (float*)alloc((size_t)N * 128 * 4);

  const int nb = (N + 255) / 256; // 391 <= 512 (k_scan_partials capacity)

  hipMemsetAsync(cur, 0, (size_t)N * 4, stream);
  k_count<<<2048, 256, 0, stream>>>(dstp, cur, E);
  k_scan_block<<<nb, 256, 0, stream>>>(cur, off, bsum, N);
  k_scan_partials<<<1, 512, 0, stream>>>(bsum, nb);
  k_scan_add<<<nb, 256, 0, stream>>>(off, bsum, N, E);
  hipMemcpyAsync(cur, off, (size_t)N * 4, hipMemcpyDeviceToDevice, stream);
  k_fill<<<2048, 256, 0, stream>>>(srcp, dstp, cur, csr, E);
  k_agg128<<<(N + 3) / 4, 256, 0, stream>>>(x, off, csr, M, N);
  k_gemm128<1><<<(N + 63) / 64, 256, 0, stream>>>(M, W1l, x, W1r, b1, H1, N);
  k_gemm128<2><<<(N + 63) / 64, 256, 0, stream>>>(H1, W2l, H1, W2r, nullptr, M, N);
  k_final<<<(N + 3) / 4, 256, 0, stream>>>(M, off, csr, b2, Wfc, bfc, out, N);
}

// Round 2
// 872.224 us; speedup vs baseline: 1.0518x; 1.0518x over previous
//
#include <hip/hip_runtime.h>
#include <math.h>

// ---------------------------------------------------------------------------
// GraphSAGE (2x SAGEConv mean + FC + sigmoid) on MI355X.
// Pipeline:
//   1) degree histogram (int atomics)
//   2) exclusive scan -> CSR offsets (3-kernel hierarchical scan)
//   3) CSR fill via 2-level binned counting sort:
//      binA: scatter packed (dst&15)<<17|src into per-bucket (dst>>4) streams
//      binB: wave-per-bucket, LDS per-node cursors, place into exact CSR slot
//      (replaces single-pass random 4B scatter that caused 16x write-amp:
//       196 MB WRITE_SIZE, 270 us -- round-1 profile)
//   4) agg128: mean-aggregate x over neighbors -> M [N,128]
//   5) gemm<1>: H1 = relu(M@W1l + x@W1r + b1)          [N,128]
//   6) gemm<2>: P  = H1 @ [W2l | W2r]                  [N,128]
//   7) final: per node, mean-aggregate P[:,0:64], add P[n,64:]+b2, relu,
//             dot Wfc, sigmoid -> out[n]
// Uses mean(h1)@W2l == mean(h1@W2l) to halve layer-2 gather bytes.
// ---------------------------------------------------------------------------

__global__ __launch_bounds__(256) void k_count(const int* __restrict__ dst,
                                               int* __restrict__ cnt, int E) {
  int stride = gridDim.x * blockDim.x;
  for (int e = blockIdx.x * blockDim.x + threadIdx.x; e < E; e += stride)
    atomicAdd(&cnt[dst[e]], 1);
}

__global__ __launch_bounds__(256) void k_scan_block(const int* __restrict__ cnt,
                                                    int* __restrict__ off,
                                                    int* __restrict__ bsum, int n) {
  __shared__ int sh[256];
  int t = threadIdx.x;
  int i = blockIdx.x * 256 + t;
  int v = (i < n) ? cnt[i] : 0;
  sh[t] = v;
  __syncthreads();
  int x = v;
  for (int d = 1; d < 256; d <<= 1) {
    int y = (t >= d) ? sh[t - d] : 0;
    __syncthreads();
    x += y;
    sh[t] = x;
    __syncthreads();
  }
  if (i < n) off[i] = x - v;          // exclusive within block
  if (t == 255) bsum[blockIdx.x] = x; // block total
}

__global__ void k_scan_partials(int* bsum, int nb) {
  // nb must be <= 512 (N=100000 -> nb=391)
  __shared__ int sh[512];
  int t = threadIdx.x;
  int v = (t < nb) ? bsum[t] : 0;
  sh[t] = v;
  __syncthreads();
  int x = v;
  for (int d = 1; d < 512; d <<= 1) {
    int y = (t >= d) ? sh[t - d] : 0;
    __syncthreads();
    x += y;
    sh[t] = x;
    __syncthreads();
  }
  if (t < nb) bsum[t] = x - v; // exclusive block base
}

__global__ __launch_bounds__(256) void k_scan_add(int* __restrict__ off,
                                                  const int* __restrict__ bsum,
                                                  int n, int total) {
  int i = blockIdx.x * 256 + threadIdx.x;
  if (i < n) off[i] += bsum[blockIdx.x];
  if (i == 0) off[n] = total;
}

// bucket cursors: bucket b covers nodes [b*16, b*16+16); start = off[b*16]
__global__ __launch_bounds__(256) void k_binit(const int* __restrict__ off,
                                               int* __restrict__ bcur, int NB) {
  int b = blockIdx.x * 256 + threadIdx.x;
  if (b < NB) bcur[b] = off[b * 16];
}

// pass A: scatter packed entries into per-bucket streams (sequential per bucket)
__global__ __launch_bounds__(256) void k_binA(const int* __restrict__ src,
                                              const int* __restrict__ dst,
                                              int* __restrict__ bcur,
                                              unsigned* __restrict__ tmp, int E) {
  int stride = gridDim.x * blockDim.x;
  for (int e = blockIdx.x * blockDim.x + threadIdx.x; e < E; e += stride) {
    int d = dst[e];
    int p = atomicAdd(&bcur[d >> 4], 1);
    tmp[p] = (unsigned)src[e] | ((unsigned)(d & 15) << 17); // src < 2^17
  }
}

// pass B: wave per bucket; 16 per-node cursors in LDS; place into exact slot
__global__ __launch_bounds__(256) void k_binB(const unsigned* __restrict__ tmp,
                                              const int* __restrict__ off,
                                              int* __restrict__ csr,
                                              int NB, int N) {
  __shared__ int c[4][16];
  int w = threadIdx.x >> 6;
  int lane = threadIdx.x & 63;
  int wid = blockIdx.x * 4 + w;
  if (wid >= NB) return;
  int n0 = wid * 16;
  int nend = min(n0 + 16, N);
  int s = off[n0], e = off[nend];
  if (lane < nend - n0) c[w][lane] = off[n0 + lane];
  __builtin_amdgcn_wave_barrier();  // order LDS write before atomics (same wave)
  for (int i = s + lane; i < e; i += 64) {
    unsigned v = tmp[i];
    int srcv = (int)(v & 0x1FFFFu);
    int dlow = (int)(v >> 17);
    int pos = atomicAdd(&c[w][dlow], 1);
    csr[pos] = srcv;
  }
}

// wave-per-node mean aggregation of 128-dim rows: M[n] = mean_{s in N(n)} x[s]
__global__ __launch_bounds__(256) void k_agg128(const float* __restrict__ x,
                                                const int* __restrict__ off,
                                                const int* __restrict__ csr,
                                                float* __restrict__ M, int n) {
  int lane = threadIdx.x & 63;
  int node = blockIdx.x * 4 + (threadIdx.x >> 6);
  if (node >= n) return;
  int s = off[node], e = off[node + 1];
  const float2* X = (const float2*)x;
  float ax0 = 0, ay0 = 0, ax1 = 0, ay1 = 0, ax2 = 0, ay2 = 0, ax3 = 0, ay3 = 0;
  int i = s;
  for (; i + 4 <= e; i += 4) {
    int s0 = csr[i], s1 = csr[i + 1], s2 = csr[i + 2], s3 = csr[i + 3];
    float2 v0 = X[(size_t)s0 * 64 + lane];
    float2 v1 = X[(size_t)s1 * 64 + lane];
    float2 v2 = X[(size_t)s2 * 64 + lane];
    float2 v3 = X[(size_t)s3 * 64 + lane];
    ax0 += v0.x; ay0 += v0.y;
    ax1 += v1.x; ay1 += v1.y;
    ax2 += v2.x; ay2 += v2.y;
    ax3 += v3.x; ay3 += v3.y;
  }
  for (; i < e; ++i) {
    int s0 = csr[i];
    float2 v0 = X[(size_t)s0 * 64 + lane];
    ax0 += v0.x; ay0 += v0.y;
  }
  int deg = e - s;
  float inv = 1.0f / (float)(deg > 0 ? deg : 1);
  float2 r;
  r.x = (ax0 + ax1 + ax2 + ax3) * inv;
  r.y = (ay0 + ay1 + ay2 + ay3) * inv;
  ((float2*)M)[(size_t)node * 64 + lane] = r;
}

// Tiled fp32 GEMM, tile 64 rows x 128 cols, K chunked by 64 in LDS.
// MODE 1: C = relu(A1@Wa + A2@Wb + bias)   (Wa,Wb: [128,128])
// MODE 2: C = A1 @ [Wa | Wb]               (Wa,Wb: [128,64]), no bias/relu
template <int MODE>
__global__ __launch_bounds__(256) void k_gemm128(const float* __restrict__ A1,
                                                 const float* __restrict__ Wa,
                                                 const float* __restrict__ A2,
                                                 const float* __restrict__ Wb,
                                                 const float* __restrict__ bias,
                                                 float* __restrict__ C, int nrows) {
  __shared__ float Al[64][68];
  __shared__ float Wl[64][128];
  int t = threadIdx.x;
  int tx = t & 15, ty = t >> 4;
  int rowbase = blockIdx.x * 64;
  float acc[4][8];
#pragma unroll
  for (int i = 0; i < 4; ++i)
#pragma unroll
    for (int j = 0; j < 8; ++j) acc[i][j] = 0.f;

  const int nmat = (MODE == 1) ? 2 : 1;
  for (int m = 0; m < nmat; ++m) {
    const float* A = (m == 0) ? A1 : A2;
    const float* W = (m == 0) ? Wa : Wb;
    (void)W;
    for (int k0 = 0; k0 < 128; k0 += 64) {
      { // stage A tile [64][64]
        int tc = t & 15, tr = t >> 4;
#pragma unroll
        for (int p = 0; p < 4; ++p) {
          int row = tr + p * 16;
          int gr = rowbase + row;
          float4 v = make_float4(0.f, 0.f, 0.f, 0.f);
          if (gr < nrows) v = *(const float4*)&A[(size_t)gr * 128 + k0 + tc * 4];
          *(float4*)&Al[row][tc * 4] = v;
        }
      }
      { // stage W tile [64][128]
        int tc = t & 31, tr = t >> 5;
#pragma unroll
        for (int p = 0; p < 8; ++p) {
          int kk = tr + p * 8;
          float4 v;
          if (MODE == 1) {
            v = *(const float4*)&W[(size_t)(k0 + kk) * 128 + tc * 4];
          } else {
            int c = tc * 4;
            if (c < 64) v = *(const float4*)&Wa[(size_t)(k0 + kk) * 64 + c];
            else        v = *(const float4*)&Wb[(size_t)(k0 + kk) * 64 + (c - 64)];
          }
          *(float4*)&Wl[kk][tc * 4] = v;
        }
      }
      __syncthreads();
#pragma unroll 4
      for (int kk = 0; kk < 64; ++kk) {
        float4 w0 = *(float4*)&Wl[kk][tx * 8];
        float4 w1 = *(float4*)&Wl[kk][tx * 8 + 4];
#pragma unroll
        for (int i2 = 0; i2 < 4; ++i2) {
          float a = Al[ty * 4 + i2][kk];
          acc[i2][0] += a * w0.x; acc[i2][1] += a * w0.y;
          acc[i2][2] += a * w0.z; acc[i2][3] += a * w0.w;
          acc[i2][4] += a * w1.x; acc[i2][5] += a * w1.y;
          acc[i2][6] += a * w1.z; acc[i2][7] += a * w1.w;
        }
      }
      __syncthreads();
    }
  }
  float4 bv0 = make_float4(0.f, 0.f, 0.f, 0.f), bv1 = bv0;
  if (MODE == 1) {
    bv0 = *(const float4*)&bias[tx * 8];
    bv1 = *(const float4*)&bias[tx * 8 + 4];
  }
#pragma unroll
  for (int i2 = 0; i2 < 4; ++i2) {
    int gr = rowbase + ty * 4 + i2;
    if (gr >= nrows) continue;
    float o[8];
#pragma unroll
    for (int j = 0; j < 8; ++j) o[j] = acc[i2][j];
    if (MODE == 1) {
      o[0] += bv0.x; o[1] += bv0.y; o[2] += bv0.z; o[3] += bv0.w;
      o[4] += bv1.x; o[5] += bv1.y; o[6] += bv1.z; o[7] += bv1.w;
#pragma unroll
      for (int j = 0; j < 8; ++j) o[j] = fmaxf(o[j], 0.f);
    }
    *(float4*)&C[(size_t)gr * 128 + tx * 8]     = make_float4(o[0], o[1], o[2], o[3]);
    *(float4*)&C[(size_t)gr * 128 + tx * 8 + 4] = make_float4(o[4], o[5], o[6], o[7]);
  }
}

// wave-per-node: mean-aggregate P[:,0:64], add P[n,64:128]+b2, relu, dot Wfc, sigmoid
__global__ __launch_bounds__(256) void k_final(const float* __restrict__ P,
                                               const int* __restrict__ off,
                                               const int* __restrict__ csr,
                                               const float* __restrict__ b2,
                                               const float* __restrict__ Wfc,
                                               const float* __restrict__ bfc,
                                               float* __restrict__ out, int n) {
  int lane = threadIdx.x & 63;
  int node = blockIdx.x * 4 + (threadIdx.x >> 6);
  if (node >= n) return;
  int s = off[node], e = off[node + 1];
  float a0 = 0, a1 = 0, a2 = 0, a3 = 0;
  int i = s;
  for (; i + 4 <= e; i += 4) {
    int s0 = csr[i], s1 = csr[i + 1], s2 = csr[i + 2], s3 = csr[i + 3];
    a0 += P[(size_t)s0 * 128 + lane];
    a1 += P[(size_t)s1 * 128 + lane];
    a2 += P[(size_t)s2 * 128 + lane];
    a3 += P[(size_t)s3 * 128 + lane];
  }
  for (; i < e; ++i) a0 += P[(size_t)csr[i] * 128 + lane];
  int deg = e - s;
  float inv = 1.0f / (float)(deg > 0 ? deg : 1);
  float h = (a0 + a1 + a2 + a3) * inv + P[(size_t)node * 128 + 64 + lane] + b2[lane];
  h = fmaxf(h, 0.f);
  float v = h * Wfc[lane];
#pragma unroll
  for (int o2 = 32; o2 > 0; o2 >>= 1) v += __shfl_xor(v, o2, 64);
  if (lane == 0) out[node] = 1.0f / (1.0f + expf(-(v + bfc[0])));
}

extern "C" void kernel_launch(void* const* d_in, const int* in_sizes, int n_in,
                              void* d_out, int out_size, void* d_ws, size_t ws_size,
                              hipStream_t stream) {
  const float* x   = (const float*)d_in[0];
  const int*   ei  = (const int*)d_in[1];
  const float* W1l = (const float*)d_in[2];
  const float* b1  = (const float*)d_in[3];
  const float* W1r = (const float*)d_in[4];
  const float* W2l = (const float*)d_in[5];
  const float* b2  = (const float*)d_in[6];
  const float* W2r = (const float*)d_in[7];
  const float* Wfc = (const float*)d_in[8];
  const float* bfc = (const float*)d_in[9];
  float* out = (float*)d_out;

  const int N = in_sizes[0] / 128;
  const int E = in_sizes[1] / 2;
  const int* srcp = ei;       // edge_index[0]
  const int* dstp = ei + E;   // edge_index[1]
  const int NB = (N + 15) / 16;

  // workspace layout (256B aligned regions)
  char* w = (char*)d_ws;
  auto alloc = [&](size_t bytes) -> void* {
    void* p = (void*)w;
    w += (bytes + 255) & ~(size_t)255;
    return p;
  };
  int*   off  = (int*)alloc((size_t)(N + 1) * 4);
  int*   cur  = (int*)alloc((size_t)N * 4);        // degree counts
  int*   bsum = (int*)alloc(4096);
  int*   bcur = (int*)alloc((size_t)NB * 4);
  int*   csr  = (int*)alloc((size_t)E * 4);
  float* M    = (float*)alloc((size_t)N * 128 * 4); // mean-agg, later reused as P
  float* H1   = (float*)alloc((size_t)N * 128 * 4);
  unsigned* tmp = (unsigned*)H1;  // lifetimes disjoint: tmp dead before gemm<1> writes H1

  const int nb = (N + 255) / 256; // 391 <= 512 (k_scan_partials capacity)

  hipMemsetAsync(cur, 0, (size_t)N * 4, stream);
  k_count<<<2048, 256, 0, stream>>>(dstp, cur, E);
  k_scan_block<<<nb, 256, 0, stream>>>(cur, off, bsum, N);
  k_scan_partials<<<1, 512, 0, stream>>>(bsum, nb);
  k_scan_add<<<nb, 256, 0, stream>>>(off, bsum, N, E);
  k_binit<<<(NB + 255) / 256, 256, 0, stream>>>(off, bcur, NB);
  k_binA<<<2048, 256, 0, stream>>>(srcp, dstp, bcur, tmp, E);
  k_binB<<<(NB + 3) / 4, 256, 0, stream>>>(tmp, off, csr, NB, N);
  k_agg128<<<(N + 3) / 4, 256, 0, stream>>>(x, off, csr, M, N);
  k_gemm128<1><<<(N + 63) / 64, 256, 0, stream>>>(M, W1l, x, W1r, b1, H1, N);
  k_gemm128<2><<<(N + 63) / 64, 256, 0, stream>>>(H1, W2l, H1, W2r, nullptr, M, N);
  k_final<<<(N + 3) / 4, 256, 0, stream>>>(M, off, csr, b2, Wfc, bfc, out, N);
}

// Round 3
// 778.392 us; speedup vs baseline: 1.1786x; 1.1205x over previous
//
#include <hip/hip_runtime.h>
#include <math.h>

// ---------------------------------------------------------------------------
// GraphSAGE (2x SAGEConv mean + FC + sigmoid) on MI355X.
// Pipeline:
//   0) cvt: x -> bf16 table xh [N,128]   (halves gather bytes; thresh 1.26e-2
//      has ~10x headroom over bf16-propagated error ~1e-3)
//   1) degree histogram (int atomics)
//   2) exclusive scan -> CSR offsets
//   3) CSR fill via 2-level binned counting sort (binA/binB; round-1 fix for
//      16x write-amp of random 4B scatter)
//   4) agg128: mean-aggregate xh over neighbors -> M [N,128] bf16
//   5) gemm<1>: H1 = relu(M@W1l + x@W1r + b1)   [N,128] fp32, bf16 A-tiles
//   6) gemm<2>: P  = H1 @ [W2l | W2r]           [N,128] bf16
//   7) final: per node, mean-aggregate P[:,0:64] (bf16 gather), add
//      P[n,64:]+b2, relu, dot Wfc, sigmoid -> out[n]
// Uses mean(h1)@W2l == mean(h1@W2l) to halve layer-2 gather bytes.
// ---------------------------------------------------------------------------

__device__ __forceinline__ unsigned bf16_rne(float f) {
  unsigned u = __float_as_uint(f);
  return (u + 0x7FFFu + ((u >> 16) & 1u)) >> 16;
}
__device__ __forceinline__ unsigned pack2(float a, float b) {
  return bf16_rne(a) | (bf16_rne(b) << 16);
}
__device__ __forceinline__ float bf16lo(unsigned u) { return __uint_as_float(u << 16); }
__device__ __forceinline__ float bf16hi(unsigned u) { return __uint_as_float(u & 0xFFFF0000u); }
__device__ __forceinline__ float bf16s(unsigned short v) { return __uint_as_float(((unsigned)v) << 16); }

// x fp32 -> xh bf16 (packed pairs)
__global__ __launch_bounds__(256) void k_cvt(const float2* __restrict__ x,
                                             unsigned* __restrict__ xh, int n2) {
  int stride = gridDim.x * 256;
  for (int i = blockIdx.x * 256 + threadIdx.x; i < n2; i += stride) {
    float2 v = x[i];
    xh[i] = pack2(v.x, v.y);
  }
}

__global__ __launch_bounds__(256) void k_count(const int* __restrict__ dst,
                                               int* __restrict__ cnt, int E) {
  int stride = gridDim.x * blockDim.x;
  for (int e = blockIdx.x * blockDim.x + threadIdx.x; e < E; e += stride)
    atomicAdd(&cnt[dst[e]], 1);
}

__global__ __launch_bounds__(256) void k_scan_block(const int* __restrict__ cnt,
                                                    int* __restrict__ off,
                                                    int* __restrict__ bsum, int n) {
  __shared__ int sh[256];
  int t = threadIdx.x;
  int i = blockIdx.x * 256 + t;
  int v = (i < n) ? cnt[i] : 0;
  sh[t] = v;
  __syncthreads();
  int x = v;
  for (int d = 1; d < 256; d <<= 1) {
    int y = (t >= d) ? sh[t - d] : 0;
    __syncthreads();
    x += y;
    sh[t] = x;
    __syncthreads();
  }
  if (i < n) off[i] = x - v;
  if (t == 255) bsum[blockIdx.x] = x;
}

__global__ void k_scan_partials(int* bsum, int nb) {
  __shared__ int sh[512];
  int t = threadIdx.x;
  int v = (t < nb) ? bsum[t] : 0;
  sh[t] = v;
  __syncthreads();
  int x = v;
  for (int d = 1; d < 512; d <<= 1) {
    int y = (t >= d) ? sh[t - d] : 0;
    __syncthreads();
    x += y;
    sh[t] = x;
    __syncthreads();
  }
  if (t < nb) bsum[t] = x - v;
}

__global__ __launch_bounds__(256) void k_scan_add(int* __restrict__ off,
                                                  const int* __restrict__ bsum,
                                                  int n, int total) {
  int i = blockIdx.x * 256 + threadIdx.x;
  if (i < n) off[i] += bsum[blockIdx.x];
  if (i == 0) off[n] = total;
}

__global__ __launch_bounds__(256) void k_binit(const int* __restrict__ off,
                                               int* __restrict__ bcur, int NB) {
  int b = blockIdx.x * 256 + threadIdx.x;
  if (b < NB) bcur[b] = off[b * 16];
}

__global__ __launch_bounds__(256) void k_binA(const int* __restrict__ src,
                                              const int* __restrict__ dst,
                                              int* __restrict__ bcur,
                                              unsigned* __restrict__ tmp, int E) {
  int stride = gridDim.x * blockDim.x;
  for (int e = blockIdx.x * blockDim.x + threadIdx.x; e < E; e += stride) {
    int d = dst[e];
    int p = atomicAdd(&bcur[d >> 4], 1);
    tmp[p] = (unsigned)src[e] | ((unsigned)(d & 15) << 17); // src < 2^17
  }
}

__global__ __launch_bounds__(256) void k_binB(const unsigned* __restrict__ tmp,
                                              const int* __restrict__ off,
                                              int* __restrict__ csr,
                                              int NB, int N) {
  __shared__ int c[4][16];
  int w = threadIdx.x >> 6;
  int lane = threadIdx.x & 63;
  int wid = blockIdx.x * 4 + w;
  if (wid >= NB) return;
  int n0 = wid * 16;
  int nend = min(n0 + 16, N);
  int s = off[n0], e = off[nend];
  if (lane < nend - n0) c[w][lane] = off[n0 + lane];
  __builtin_amdgcn_wave_barrier();
  for (int i = s + lane; i < e; i += 64) {
    unsigned v = tmp[i];
    int srcv = (int)(v & 0x1FFFFu);
    int dlow = (int)(v >> 17);
    int pos = atomicAdd(&c[w][dlow], 1);
    csr[pos] = srcv;
  }
}

// wave-per-node mean aggregation of bf16 128-dim rows -> M (bf16)
__global__ __launch_bounds__(256) void k_agg128(const unsigned* __restrict__ xh,
                                                const int* __restrict__ off,
                                                const int* __restrict__ csr,
                                                unsigned* __restrict__ M, int n) {
  int lane = threadIdx.x & 63;
  int node = blockIdx.x * 4 + (threadIdx.x >> 6);
  if (node >= n) return;
  int s = off[node], e = off[node + 1];
  float ax0 = 0, ay0 = 0, ax1 = 0, ay1 = 0, ax2 = 0, ay2 = 0, ax3 = 0, ay3 = 0;
  int i = s;
  for (; i + 4 <= e; i += 4) {
    int s0 = csr[i], s1 = csr[i + 1], s2 = csr[i + 2], s3 = csr[i + 3];
    unsigned u0 = xh[(size_t)s0 * 64 + lane];
    unsigned u1 = xh[(size_t)s1 * 64 + lane];
    unsigned u2 = xh[(size_t)s2 * 64 + lane];
    unsigned u3 = xh[(size_t)s3 * 64 + lane];
    ax0 += bf16lo(u0); ay0 += bf16hi(u0);
    ax1 += bf16lo(u1); ay1 += bf16hi(u1);
    ax2 += bf16lo(u2); ay2 += bf16hi(u2);
    ax3 += bf16lo(u3); ay3 += bf16hi(u3);
  }
  for (; i < e; ++i) {
    unsigned u0 = xh[(size_t)csr[i] * 64 + lane];
    ax0 += bf16lo(u0); ay0 += bf16hi(u0);
  }
  int deg = e - s;
  float inv = 1.0f / (float)(deg > 0 ? deg : 1);
  float rx = (ax0 + ax1 + ax2 + ax3) * inv;
  float ry = (ay0 + ay1 + ay2 + ay3) * inv;
  M[(size_t)node * 64 + lane] = pack2(rx, ry);
}

// Tiled GEMM, tile 64 rows x 128 cols, K chunked by 64 in LDS, fp32 compute.
// MODE 1: C(fp32) = relu(A1@Wa + A2@Wb + bias); A1,A2 bf16 [N,128]; Wa,Wb [128,128]
// MODE 2: C(bf16) = A1 @ [Wa | Wb]; A1 fp32 [N,128]; Wa,Wb [128,64]
template <int MODE>
__global__ __launch_bounds__(256) void k_gemm(const void* __restrict__ A1v,
                                              const float* __restrict__ Wa,
                                              const void* __restrict__ A2v,
                                              const float* __restrict__ Wb,
                                              const float* __restrict__ bias,
                                              void* __restrict__ Cv, int nrows) {
  __shared__ float Al[64][68];
  __shared__ float Wl[64][128];
  int t = threadIdx.x;
  int tx = t & 15, ty = t >> 4;
  int rowbase = blockIdx.x * 64;
  float acc[4][8];
#pragma unroll
  for (int i = 0; i < 4; ++i)
#pragma unroll
    for (int j = 0; j < 8; ++j) acc[i][j] = 0.f;

  const int nmat = (MODE == 1) ? 2 : 1;
  for (int m = 0; m < nmat; ++m) {
    for (int k0 = 0; k0 < 128; k0 += 64) {
      if (MODE == 1) { // stage A tile [64][64] from bf16 source
        const unsigned* Ab = (const unsigned*)((m == 0) ? A1v : A2v);
        int tc = t & 7, tr = t >> 3; // 8 thr/row (uint4 = 8 elems), 32 rows/pass
#pragma unroll
        for (int p = 0; p < 2; ++p) {
          int row = tr + p * 32;
          int gr = rowbase + row;
          uint4 v = make_uint4(0, 0, 0, 0);
          if (gr < nrows) v = *(const uint4*)&Ab[(size_t)gr * 64 + (k0 >> 1) + tc * 4];
          *(float4*)&Al[row][tc * 8]     = make_float4(bf16lo(v.x), bf16hi(v.x), bf16lo(v.y), bf16hi(v.y));
          *(float4*)&Al[row][tc * 8 + 4] = make_float4(bf16lo(v.z), bf16hi(v.z), bf16lo(v.w), bf16hi(v.w));
        }
      } else { // stage A tile from fp32 source
        const float* A = (const float*)A1v;
        int tc = t & 15, tr = t >> 4;
#pragma unroll
        for (int p = 0; p < 4; ++p) {
          int row = tr + p * 16;
          int gr = rowbase + row;
          float4 v = make_float4(0.f, 0.f, 0.f, 0.f);
          if (gr < nrows) v = *(const float4*)&A[(size_t)gr * 128 + k0 + tc * 4];
          *(float4*)&Al[row][tc * 4] = v;
        }
      }
      { // stage W tile [64][128]
        int tc = t & 31, tr = t >> 5;
        const float* W = (m == 0) ? Wa : Wb;
#pragma unroll
        for (int p = 0; p < 8; ++p) {
          int kk = tr + p * 8;
          float4 v;
          if (MODE == 1) {
            v = *(const float4*)&W[(size_t)(k0 + kk) * 128 + tc * 4];
          } else {
            int c = tc * 4;
            if (c < 64) v = *(const float4*)&Wa[(size_t)(k0 + kk) * 64 + c];
            else        v = *(const float4*)&Wb[(size_t)(k0 + kk) * 64 + (c - 64)];
          }
          *(float4*)&Wl[kk][tc * 4] = v;
        }
      }
      __syncthreads();
#pragma unroll 4
      for (int kk = 0; kk < 64; ++kk) {
        float4 w0 = *(float4*)&Wl[kk][tx * 8];
        float4 w1 = *(float4*)&Wl[kk][tx * 8 + 4];
#pragma unroll
        for (int i2 = 0; i2 < 4; ++i2) {
          float a = Al[ty * 4 + i2][kk];
          acc[i2][0] += a * w0.x; acc[i2][1] += a * w0.y;
          acc[i2][2] += a * w0.z; acc[i2][3] += a * w0.w;
          acc[i2][4] += a * w1.x; acc[i2][5] += a * w1.y;
          acc[i2][6] += a * w1.z; acc[i2][7] += a * w1.w;
        }
      }
      __syncthreads();
    }
  }
  float4 bv0 = make_float4(0.f, 0.f, 0.f, 0.f), bv1 = bv0;
  if (MODE == 1) {
    bv0 = *(const float4*)&bias[tx * 8];
    bv1 = *(const float4*)&bias[tx * 8 + 4];
  }
#pragma unroll
  for (int i2 = 0; i2 < 4; ++i2) {
    int gr = rowbase + ty * 4 + i2;
    if (gr >= nrows) continue;
    float o[8];
#pragma unroll
    for (int j = 0; j < 8; ++j) o[j] = acc[i2][j];
    if (MODE == 1) {
      o[0] += bv0.x; o[1] += bv0.y; o[2] += bv0.z; o[3] += bv0.w;
      o[4] += bv1.x; o[5] += bv1.y; o[6] += bv1.z; o[7] += bv1.w;
#pragma unroll
      for (int j = 0; j < 8; ++j) o[j] = fmaxf(o[j], 0.f);
      float* C = (float*)Cv;
      *(float4*)&C[(size_t)gr * 128 + tx * 8]     = make_float4(o[0], o[1], o[2], o[3]);
      *(float4*)&C[(size_t)gr * 128 + tx * 8 + 4] = make_float4(o[4], o[5], o[6], o[7]);
    } else {
      unsigned* C = (unsigned*)Cv;
      *(uint4*)&C[(size_t)gr * 64 + tx * 4] =
          make_uint4(pack2(o[0], o[1]), pack2(o[2], o[3]), pack2(o[4], o[5]), pack2(o[6], o[7]));
    }
  }
}

// wave-per-node: mean-aggregate Ph[:,0:64] (bf16), add Ph[n,64:]+b2, relu,
// dot Wfc, sigmoid
__global__ __launch_bounds__(256) void k_final(const unsigned short* __restrict__ Ph,
                                               const int* __restrict__ off,
                                               const int* __restrict__ csr,
                                               const float* __restrict__ b2,
                                               const float* __restrict__ Wfc,
                                               const float* __restrict__ bfc,
                                               float* __restrict__ out, int n) {
  int lane = threadIdx.x & 63;
  int node = blockIdx.x * 4 + (threadIdx.x >> 6);
  if (node >= n) return;
  int s = off[node], e = off[node + 1];
  float a0 = 0, a1 = 0, a2 = 0, a3 = 0;
  int i = s;
  for (; i + 4 <= e; i += 4) {
    int s0 = csr[i], s1 = csr[i + 1], s2 = csr[i + 2], s3 = csr[i + 3];
    a0 += bf16s(Ph[(size_t)s0 * 128 + lane]);
    a1 += bf16s(Ph[(size_t)s1 * 128 + lane]);
    a2 += bf16s(Ph[(size_t)s2 * 128 + lane]);
    a3 += bf16s(Ph[(size_t)s3 * 128 + lane]);
  }
  for (; i < e; ++i) a0 += bf16s(Ph[(size_t)csr[i] * 128 + lane]);
  int deg = e - s;
  float inv = 1.0f / (float)(deg > 0 ? deg : 1);
  float h = (a0 + a1 + a2 + a3) * inv + bf16s(Ph[(size_t)node * 128 + 64 + lane]) + b2[lane];
  h = fmaxf(h, 0.f);
  float v = h * Wfc[lane];
#pragma unroll
  for (int o2 = 32; o2 > 0; o2 >>= 1) v += __shfl_xor(v, o2, 64);
  if (lane == 0) out[node] = 1.0f / (1.0f + expf(-(v + bfc[0])));
}

extern "C" void kernel_launch(void* const* d_in, const int* in_sizes, int n_in,
                              void* d_out, int out_size, void* d_ws, size_t ws_size,
                              hipStream_t stream) {
  const float* x   = (const float*)d_in[0];
  const int*   ei  = (const int*)d_in[1];
  const float* W1l = (const float*)d_in[2];
  const float* b1  = (const float*)d_in[3];
  const float* W1r = (const float*)d_in[4];
  const float* W2l = (const float*)d_in[5];
  const float* b2  = (const float*)d_in[6];
  const float* W2r = (const float*)d_in[7];
  const float* Wfc = (const float*)d_in[8];
  const float* bfc = (const float*)d_in[9];
  float* out = (float*)d_out;

  const int N = in_sizes[0] / 128;
  const int E = in_sizes[1] / 2;
  const int* srcp = ei;       // edge_index[0]
  const int* dstp = ei + E;   // edge_index[1]
  const int NB = (N + 15) / 16;

  // workspace layout (256B aligned regions), ~116 MB total
  char* w = (char*)d_ws;
  auto alloc = [&](size_t bytes) -> void* {
    void* p = (void*)w;
    w += (bytes + 255) & ~(size_t)255;
    return p;
  };
  int*      off  = (int*)alloc((size_t)(N + 1) * 4);
  int*      cur  = (int*)alloc((size_t)N * 4);
  int*      bsum = (int*)alloc(4096);
  int*      bcur = (int*)alloc((size_t)NB * 4);
  int*      csr  = (int*)alloc((size_t)E * 4);
  unsigned* xh   = (unsigned*)alloc((size_t)N * 64 * 4);  // bf16 x, packed pairs
  unsigned* M    = (unsigned*)alloc((size_t)N * 64 * 4);  // bf16 mean-agg; later Ph (bf16 P)
  float*    H1   = (float*)alloc((size_t)N * 128 * 4);
  unsigned* tmp  = (unsigned*)H1;  // lifetimes disjoint: tmp dead before gemm<1> writes H1

  const int nb = (N + 255) / 256; // <= 512 (k_scan_partials capacity)

  hipMemsetAsync(cur, 0, (size_t)N * 4, stream);
  k_cvt<<<1024, 256, 0, stream>>>((const float2*)x, xh, N * 64);
  k_count<<<2048, 256, 0, stream>>>(dstp, cur, E);
  k_scan_block<<<nb, 256, 0, stream>>>(cur, off, bsum, N);
  k_scan_partials<<<1, 512, 0, stream>>>(bsum, nb);
  k_scan_add<<<nb, 256, 0, stream>>>(off, bsum, N, E);
  k_binit<<<(NB + 255) / 256, 256, 0, stream>>>(off, bcur, NB);
  k_binA<<<2048, 256, 0, stream>>>(srcp, dstp, bcur, tmp, E);
  k_binB<<<(NB + 3) / 4, 256, 0, stream>>>(tmp, off, csr, NB, N);
  k_agg128<<<(N + 3) / 4, 256, 0, stream>>>(xh, off, csr, M, N);
  k_gemm<1><<<(N + 63) / 64, 256, 0, stream>>>(M, W1l, xh, W1r, b1, H1, N);
  k_gemm<2><<<(N + 63) / 64, 256, 0, stream>>>(H1, W2l, nullptr, W2r, nullptr, M, N);
  k_final<<<(N + 3) / 4, 256, 0, stream>>>((const unsigned short*)M, off, csr, b2, Wfc, bfc, out, N);
}